// Round 1
// baseline (2235.564 us; speedup 1.0000x reference)
//
#include <hip/hip_runtime.h>
#include <cmath>

#define N_ENT  50000
#define N_RELS 16
#define N_EDGE 1000000
#define DIM    64
#define OUT_STRIDE 176

// ---------------------------------------------------------------------------
// K1: histogram of dst -> counts
// ---------------------------------------------------------------------------
__global__ void hist_kernel(const int* __restrict__ dst,
                            int* __restrict__ counts, int n) {
    int i = blockIdx.x * blockDim.x + threadIdx.x;
    if (i < n) atomicAdd(&counts[dst[i]], 1);
}

// ---------------------------------------------------------------------------
// K2: exclusive scan counts -> row_ptr (single block, 1024 threads)
// ---------------------------------------------------------------------------
__global__ void scan_kernel(const int* __restrict__ counts,
                            int* __restrict__ row_ptr, int n) {
    __shared__ int sums[1024];
    int t = threadIdx.x;
    int chunk = (n + 1023) / 1024;
    int start = t * chunk;
    int end = start + chunk; if (end > n) end = n;
    int s = 0;
    for (int i = start; i < end && i >= 0; ++i) s += counts[i];
    sums[t] = s;
    __syncthreads();
    // Hillis-Steele inclusive scan
    for (int off = 1; off < 1024; off <<= 1) {
        int v = (t >= off) ? sums[t - off] : 0;
        __syncthreads();
        sums[t] += v;
        __syncthreads();
    }
    int prefix = (t == 0) ? 0 : sums[t - 1];
    for (int i = start; i < end; ++i) {
        row_ptr[i] = prefix;
        prefix += counts[i];
    }
    if (end == n) row_ptr[n] = prefix;   // several threads may write; same value
}

// ---------------------------------------------------------------------------
// K3: attention logits (one wave per edge) fused with CSR fill.
// att[e] = sum_j (ent[src] @ W_r)[j] * tanh((ent[dst] @ W_r)[j] + rel[r][j])
// ---------------------------------------------------------------------------
__global__ void att_kernel(const float* __restrict__ ent,
                           const float* __restrict__ rel,
                           const float* __restrict__ W_R,
                           const int* __restrict__ src,
                           const int* __restrict__ dst,
                           const int* __restrict__ etype,
                           const int* __restrict__ row_ptr,
                           int* __restrict__ cursor,
                           float* __restrict__ att_csr,
                           int* __restrict__ src_csr,
                           int n_edge) {
    int wid  = (blockIdx.x * blockDim.x + threadIdx.x) >> 6;
    int lane = threadIdx.x & 63;
    if (wid >= n_edge) return;

    int s = src[wid];
    int d = dst[wid];
    int r = etype[wid];
    const float* Wr = W_R + (size_t)r * DIM * DIM;

    float et = ent[(size_t)s * DIM + lane];   // coalesced 256B row
    float eh = ent[(size_t)d * DIM + lane];

    float acc_t = 0.f, acc_h = 0.f;
#pragma unroll
    for (int k = 0; k < DIM; ++k) {
        float w  = Wr[k * DIM + lane];        // coalesced, L1/L2-hot
        float tk = __shfl(et, k, 64);         // broadcast (readlane)
        float hk = __shfl(eh, k, 64);
        acc_t = fmaf(tk, w, acc_t);
        acc_h = fmaf(hk, w, acc_h);
    }
    float th   = tanhf(acc_h + rel[r * DIM + lane]);
    float prod = acc_t * th;
#pragma unroll
    for (int off = 32; off > 0; off >>= 1)
        prod += __shfl_down(prod, off, 64);

    if (lane == 0) {
        int pos = row_ptr[d] + atomicAdd(&cursor[d], 1);
        att_csr[pos] = prod;
        src_csr[pos] = s;
    }
}

// ---------------------------------------------------------------------------
// K4: edge softmax per dst node (one wave per node), in-place att_csr -> a_csr
// ---------------------------------------------------------------------------
__global__ void softmax_kernel(const int* __restrict__ row_ptr,
                               float* __restrict__ a_csr, int n_node) {
    int wid  = (blockIdx.x * blockDim.x + threadIdx.x) >> 6;
    int lane = threadIdx.x & 63;
    if (wid >= n_node) return;
    int start = row_ptr[wid], end = row_ptr[wid + 1];

    float m = -INFINITY;
    for (int i = start + lane; i < end; i += 64) m = fmaxf(m, a_csr[i]);
#pragma unroll
    for (int off = 32; off > 0; off >>= 1)
        m = fmaxf(m, __shfl_xor(m, off, 64));

    float ssum = 0.f;
    for (int i = start + lane; i < end; i += 64) {
        float e = expf(a_csr[i] - m);
        a_csr[i] = e;
        ssum += e;
    }
#pragma unroll
    for (int off = 32; off > 0; off >>= 1)
        ssum += __shfl_xor(ssum, off, 64);

    if (end > start) {
        float inv = 1.0f / ssum;
        for (int i = start + lane; i < end; i += 64) a_csr[i] *= inv;
    }
}

// ---------------------------------------------------------------------------
// K5: copy raw ent_embed into out[:, 0:64]
// ---------------------------------------------------------------------------
__global__ void copy_ent_kernel(const float* __restrict__ ent,
                                float* __restrict__ out, int total) {
    int i = blockIdx.x * blockDim.x + threadIdx.x;
    if (i >= total) return;
    int n = i >> 6, c = i & 63;
    out[(size_t)n * OUT_STRIDE + c] = ent[i];
}

// ---------------------------------------------------------------------------
// K6: bi-interaction layer (one wave per node).
//   acc = sum_edges a * h[src]           (N_h row, kept in registers)
//   out = leaky(( h+acc ) @ W1 + b1) + leaky(( h*acc ) @ W2 + b2)
//   h_out = out (unnormalized), out_buf gets l2-normalized row.
// ---------------------------------------------------------------------------
template <int D_IN, int D_OUT>
__global__ void layer_kernel(const float* __restrict__ h_in,
                             const float* __restrict__ W1,
                             const float* __restrict__ b1,
                             const float* __restrict__ W2,
                             const float* __restrict__ b2,
                             const int* __restrict__ row_ptr,
                             const float* __restrict__ a_csr,
                             const int* __restrict__ src_csr,
                             float* __restrict__ h_out,   // may be null
                             float* __restrict__ out_buf,
                             int out_col, int n_node) {
    int wid  = (blockIdx.x * blockDim.x + threadIdx.x) >> 6;
    int lane = threadIdx.x & 63;
    if (wid >= n_node) return;

    float hval = (lane < D_IN) ? h_in[(size_t)wid * D_IN + lane] : 0.f;

    int start = row_ptr[wid], end = row_ptr[wid + 1];
    float acc = 0.f;
    for (int p = start; p < end; ++p) {
        float av = a_csr[p];
        int   si = src_csr[p];
        float hs = (lane < D_IN) ? h_in[(size_t)si * D_IN + lane] : 0.f;
        acc = fmaf(av, hs, acc);
    }

    float u = hval + acc;   // (h + N_h)
    float v = hval * acc;   // (h * N_h)

    float o1 = (lane < D_OUT) ? b1[lane] : 0.f;
    float o2 = (lane < D_OUT) ? b2[lane] : 0.f;
#pragma unroll
    for (int k = 0; k < D_IN; ++k) {
        float uk = __shfl(u, k, 64);
        float vk = __shfl(v, k, 64);
        if (lane < D_OUT) {
            o1 = fmaf(uk, W1[k * D_OUT + lane], o1);
            o2 = fmaf(vk, W2[k * D_OUT + lane], o2);
        }
    }
    float r1 = (o1 >= 0.f) ? o1 : 0.01f * o1;
    float r2 = (o2 >= 0.f) ? o2 : 0.01f * o2;
    float res = (lane < D_OUT) ? (r1 + r2) : 0.f;

    float sq = res * res;
#pragma unroll
    for (int off = 32; off > 0; off >>= 1)
        sq += __shfl_xor(sq, off, 64);
    float nrm  = sqrtf(sq);
    float resn = res / fmaxf(nrm, 1e-12f);

    if (lane < D_OUT) {
        if (h_out) h_out[(size_t)wid * D_OUT + lane] = res;
        out_buf[(size_t)wid * OUT_STRIDE + out_col + lane] = resn;
    }
}

// ---------------------------------------------------------------------------
extern "C" void kernel_launch(void* const* d_in, const int* in_sizes, int n_in,
                              void* d_out, int out_size, void* d_ws, size_t ws_size,
                              hipStream_t stream) {
    const float* ent  = (const float*)d_in[0];
    const float* rel  = (const float*)d_in[1];
    const float* W_R  = (const float*)d_in[2];
    const float* W1_0 = (const float*)d_in[3];
    const float* b1_0 = (const float*)d_in[4];
    const float* W2_0 = (const float*)d_in[5];
    const float* b2_0 = (const float*)d_in[6];
    const float* W1_1 = (const float*)d_in[7];
    const float* b1_1 = (const float*)d_in[8];
    const float* W2_1 = (const float*)d_in[9];
    const float* b2_1 = (const float*)d_in[10];
    const float* W1_2 = (const float*)d_in[11];
    const float* b1_2 = (const float*)d_in[12];
    const float* W2_2 = (const float*)d_in[13];
    const float* b2_2 = (const float*)d_in[14];
    const int*   src   = (const int*)d_in[15];
    const int*   dst   = (const int*)d_in[16];
    const int*   etype = (const int*)d_in[17];
    float* out = (float*)d_out;

    // workspace layout (all offsets multiple of 256B)
    char* w = (char*)d_ws;
    float* att_csr = (float*)w;            w += (size_t)N_EDGE * 4;         // 4 MB (becomes a_csr)
    int*   src_csr = (int*)w;              w += (size_t)N_EDGE * 4;         // 4 MB
    int*   counts  = (int*)w;              w += (size_t)(N_ENT + 64) * 4;
    int*   row_ptr = (int*)w;              w += (size_t)(N_ENT + 64) * 4;
    int*   cursor  = (int*)w;              w += (size_t)(N_ENT + 64) * 4;
    float* h1      = (float*)w;            w += (size_t)N_ENT * 64 * 4;     // 12.8 MB
    float* h2      = (float*)w;            w += (size_t)N_ENT * 32 * 4;     // 6.4 MB

    hipMemsetAsync(counts, 0, (size_t)N_ENT * 4, stream);
    hipMemsetAsync(cursor, 0, (size_t)N_ENT * 4, stream);

    // K1: histogram
    hist_kernel<<<(N_EDGE + 255) / 256, 256, 0, stream>>>(dst, counts, N_EDGE);
    // K2: scan
    scan_kernel<<<1, 1024, 0, stream>>>(counts, row_ptr, N_ENT);
    // K3: attention + CSR fill (1 wave/edge, 4 edges per 256-thread block)
    att_kernel<<<(N_EDGE + 3) / 4, 256, 0, stream>>>(
        ent, rel, W_R, src, dst, etype, row_ptr, cursor, att_csr, src_csr, N_EDGE);
    // K4: edge softmax per node
    softmax_kernel<<<(N_ENT + 3) / 4, 256, 0, stream>>>(row_ptr, att_csr, N_ENT);
    // K5: out[:, 0:64] = ent_embed
    copy_ent_kernel<<<(N_ENT * DIM + 255) / 256, 256, 0, stream>>>(ent, out, N_ENT * DIM);
    // K6: three bi-interaction layers
    layer_kernel<64, 64><<<(N_ENT + 3) / 4, 256, 0, stream>>>(
        ent, W1_0, b1_0, W2_0, b2_0, row_ptr, att_csr, src_csr, h1, out, 64, N_ENT);
    layer_kernel<64, 32><<<(N_ENT + 3) / 4, 256, 0, stream>>>(
        h1, W1_1, b1_1, W2_1, b2_1, row_ptr, att_csr, src_csr, h2, out, 128, N_ENT);
    layer_kernel<32, 16><<<(N_ENT + 3) / 4, 256, 0, stream>>>(
        h2, W1_2, b1_2, W2_2, b2_2, row_ptr, att_csr, src_csr, nullptr, out, 160, N_ENT);
}

// Round 2
// 1582.967 us; speedup vs baseline: 1.4123x; 1.4123x over previous
//
#include <hip/hip_runtime.h>
#include <hip/hip_bf16.h>
#include <cmath>

#define N_ENT  50000
#define N_RELS 16
#define N_EDGE 1000000
#define DIM    64
#define OUT_STRIDE 176

// ---------------------------------------------------------------------------
// K1: histogram of dst -> counts
// ---------------------------------------------------------------------------
__global__ void hist_kernel(const int* __restrict__ dst,
                            int* __restrict__ counts, int n) {
    int i = blockIdx.x * blockDim.x + threadIdx.x;
    if (i < n) atomicAdd(&counts[dst[i]], 1);
}

// ---------------------------------------------------------------------------
// K2: exclusive scan counts -> row_ptr (single block, 1024 threads)
// ---------------------------------------------------------------------------
__global__ void scan_kernel(const int* __restrict__ counts,
                            int* __restrict__ row_ptr, int n) {
    __shared__ int sums[1024];
    int t = threadIdx.x;
    int chunk = (n + 1023) / 1024;
    int start = t * chunk;
    int end = start + chunk; if (end > n) end = n;
    int s = 0;
    for (int i = start; i < end && i >= 0; ++i) s += counts[i];
    sums[t] = s;
    __syncthreads();
    for (int off = 1; off < 1024; off <<= 1) {
        int v = (t >= off) ? sums[t - off] : 0;
        __syncthreads();
        sums[t] += v;
        __syncthreads();
    }
    int prefix = (t == 0) ? 0 : sums[t - 1];
    for (int i = start; i < end; ++i) {
        row_ptr[i] = prefix;
        prefix += counts[i];
    }
    if (end == n) row_ptr[n] = prefix;
}

// ---------------------------------------------------------------------------
// K3a: proj[r][n][:] = ent[n][:] @ W_R[r]   (fp32 compute, bf16 store)
// One wave per row-group; W_R column j held in 64 VGPRs of lane j.
// 4-row ILP to break the serial fma-accumulate chain.
// ---------------------------------------------------------------------------
__global__ void proj_kernel(const float* __restrict__ ent,
                            const float* __restrict__ W_R,
                            __hip_bfloat16* __restrict__ proj) {
    int r    = blockIdx.x;
    int lane = threadIdx.x & 63;
    int wave = blockIdx.y * (blockDim.x >> 6) + (threadIdx.x >> 6);
    int nwaves = gridDim.y * (blockDim.x >> 6);

    const float* Wr = W_R + (size_t)r * DIM * DIM;
    float Wcol[DIM];
#pragma unroll
    for (int k = 0; k < DIM; ++k) Wcol[k] = Wr[k * DIM + lane];

    __hip_bfloat16* projr = proj + (size_t)r * N_ENT * DIM;
    int chunk = (N_ENT + nwaves - 1) / nwaves;
    int beg = wave * chunk;
    int end = beg + chunk; if (end > N_ENT) end = N_ENT;
    if (beg >= end) return;

    int n = beg;
    for (; n + 4 <= end; n += 4) {
        float x0 = ent[(size_t)(n + 0) * DIM + lane];
        float x1 = ent[(size_t)(n + 1) * DIM + lane];
        float x2 = ent[(size_t)(n + 2) * DIM + lane];
        float x3 = ent[(size_t)(n + 3) * DIM + lane];
        float a0 = 0.f, a1 = 0.f, a2 = 0.f, a3 = 0.f;
#pragma unroll
        for (int k = 0; k < DIM; ++k) {
            float w = Wcol[k];
            a0 = fmaf(__shfl(x0, k, 64), w, a0);
            a1 = fmaf(__shfl(x1, k, 64), w, a1);
            a2 = fmaf(__shfl(x2, k, 64), w, a2);
            a3 = fmaf(__shfl(x3, k, 64), w, a3);
        }
        projr[(size_t)(n + 0) * DIM + lane] = __float2bfloat16(a0);
        projr[(size_t)(n + 1) * DIM + lane] = __float2bfloat16(a1);
        projr[(size_t)(n + 2) * DIM + lane] = __float2bfloat16(a2);
        projr[(size_t)(n + 3) * DIM + lane] = __float2bfloat16(a3);
    }
    for (; n < end; ++n) {
        float x = ent[(size_t)n * DIM + lane];
        float a = 0.f;
#pragma unroll
        for (int k = 0; k < DIM; ++k)
            a = fmaf(__shfl(x, k, 64), Wcol[k], a);
        projr[(size_t)n * DIM + lane] = __float2bfloat16(a);
    }
}

// ---------------------------------------------------------------------------
// K3b: per-edge attention logit from precomputed proj (one wave per edge),
// fused with CSR fill. tanh via fast exp: tanh(x) = 1 - 2/(e^{2x}+1).
// ---------------------------------------------------------------------------
__global__ void att_edge_kernel(const __hip_bfloat16* __restrict__ proj,
                                const float* __restrict__ rel,
                                const int* __restrict__ src,
                                const int* __restrict__ dst,
                                const int* __restrict__ etype,
                                const int* __restrict__ row_ptr,
                                int* __restrict__ cursor,
                                float* __restrict__ att_csr,
                                int* __restrict__ src_csr,
                                int n_edge) {
    int wid  = (blockIdx.x * blockDim.x + threadIdx.x) >> 6;
    int lane = threadIdx.x & 63;
    if (wid >= n_edge) return;

    int s = src[wid];
    int d = dst[wid];
    int r = etype[wid];
    const __hip_bfloat16* pt = proj + ((size_t)r * N_ENT + s) * DIM;
    const __hip_bfloat16* ph = proj + ((size_t)r * N_ENT + d) * DIM;
    float t = __bfloat162float(pt[lane]);
    float h = __bfloat162float(ph[lane]);
    float x = h + rel[r * DIM + lane];
    float e2x = __expf(2.f * x);
    float th  = 1.f - 2.f / (e2x + 1.f);
    float prod = t * th;
#pragma unroll
    for (int off = 32; off > 0; off >>= 1)
        prod += __shfl_down(prod, off, 64);

    if (lane == 0) {
        int pos = row_ptr[d] + atomicAdd(&cursor[d], 1);
        att_csr[pos] = prod;
        src_csr[pos] = s;
    }
}

// ---------------------------------------------------------------------------
// K3-fallback: round-1 per-edge matvec attention (used only if ws too small)
// ---------------------------------------------------------------------------
__global__ void att_kernel(const float* __restrict__ ent,
                           const float* __restrict__ rel,
                           const float* __restrict__ W_R,
                           const int* __restrict__ src,
                           const int* __restrict__ dst,
                           const int* __restrict__ etype,
                           const int* __restrict__ row_ptr,
                           int* __restrict__ cursor,
                           float* __restrict__ att_csr,
                           int* __restrict__ src_csr,
                           int n_edge) {
    int wid  = (blockIdx.x * blockDim.x + threadIdx.x) >> 6;
    int lane = threadIdx.x & 63;
    if (wid >= n_edge) return;

    int s = src[wid];
    int d = dst[wid];
    int r = etype[wid];
    const float* Wr = W_R + (size_t)r * DIM * DIM;

    float et = ent[(size_t)s * DIM + lane];
    float eh = ent[(size_t)d * DIM + lane];

    float acc_t = 0.f, acc_h = 0.f;
#pragma unroll
    for (int k = 0; k < DIM; ++k) {
        float w  = Wr[k * DIM + lane];
        acc_t = fmaf(__shfl(et, k, 64), w, acc_t);
        acc_h = fmaf(__shfl(eh, k, 64), w, acc_h);
    }
    float xx = acc_h + rel[r * DIM + lane];
    float e2x = __expf(2.f * xx);
    float th  = 1.f - 2.f / (e2x + 1.f);
    float prod = acc_t * th;
#pragma unroll
    for (int off = 32; off > 0; off >>= 1)
        prod += __shfl_down(prod, off, 64);

    if (lane == 0) {
        int pos = row_ptr[d] + atomicAdd(&cursor[d], 1);
        att_csr[pos] = prod;
        src_csr[pos] = s;
    }
}

// ---------------------------------------------------------------------------
// K4: edge softmax per dst node (one wave per node), in-place
// ---------------------------------------------------------------------------
__global__ void softmax_kernel(const int* __restrict__ row_ptr,
                               float* __restrict__ a_csr, int n_node) {
    int wid  = (blockIdx.x * blockDim.x + threadIdx.x) >> 6;
    int lane = threadIdx.x & 63;
    if (wid >= n_node) return;
    int start = row_ptr[wid], end = row_ptr[wid + 1];

    float m = -INFINITY;
    for (int i = start + lane; i < end; i += 64) m = fmaxf(m, a_csr[i]);
#pragma unroll
    for (int off = 32; off > 0; off >>= 1)
        m = fmaxf(m, __shfl_xor(m, off, 64));

    float ssum = 0.f;
    for (int i = start + lane; i < end; i += 64) {
        float e = expf(a_csr[i] - m);
        a_csr[i] = e;
        ssum += e;
    }
#pragma unroll
    for (int off = 32; off > 0; off >>= 1)
        ssum += __shfl_xor(ssum, off, 64);

    if (end > start) {
        float inv = 1.0f / ssum;
        for (int i = start + lane; i < end; i += 64) a_csr[i] *= inv;
    }
}

// ---------------------------------------------------------------------------
// K5: copy raw ent_embed into out[:, 0:64]
// ---------------------------------------------------------------------------
__global__ void copy_ent_kernel(const float* __restrict__ ent,
                                float* __restrict__ out, int total) {
    int i = blockIdx.x * blockDim.x + threadIdx.x;
    if (i >= total) return;
    int n = i >> 6, c = i & 63;
    out[(size_t)n * OUT_STRIDE + c] = ent[i];
}

// ---------------------------------------------------------------------------
// K6: bi-interaction layer (one wave per node)
// ---------------------------------------------------------------------------
template <int D_IN, int D_OUT>
__global__ void layer_kernel(const float* __restrict__ h_in,
                             const float* __restrict__ W1,
                             const float* __restrict__ b1,
                             const float* __restrict__ W2,
                             const float* __restrict__ b2,
                             const int* __restrict__ row_ptr,
                             const float* __restrict__ a_csr,
                             const int* __restrict__ src_csr,
                             float* __restrict__ h_out,   // may be null
                             float* __restrict__ out_buf,
                             int out_col, int n_node) {
    int wid  = (blockIdx.x * blockDim.x + threadIdx.x) >> 6;
    int lane = threadIdx.x & 63;
    if (wid >= n_node) return;

    float hval = (lane < D_IN) ? h_in[(size_t)wid * D_IN + lane] : 0.f;

    int start = row_ptr[wid], end = row_ptr[wid + 1];
    float acc = 0.f;
    for (int p = start; p < end; ++p) {
        float av = a_csr[p];
        int   si = src_csr[p];
        float hs = (lane < D_IN) ? h_in[(size_t)si * D_IN + lane] : 0.f;
        acc = fmaf(av, hs, acc);
    }

    float u = hval + acc;
    float v = hval * acc;

    float o1 = (lane < D_OUT) ? b1[lane] : 0.f;
    float o2 = (lane < D_OUT) ? b2[lane] : 0.f;
#pragma unroll
    for (int k = 0; k < D_IN; ++k) {
        float uk = __shfl(u, k, 64);
        float vk = __shfl(v, k, 64);
        if (lane < D_OUT) {
            o1 = fmaf(uk, W1[k * D_OUT + lane], o1);
            o2 = fmaf(vk, W2[k * D_OUT + lane], o2);
        }
    }
    float r1 = (o1 >= 0.f) ? o1 : 0.01f * o1;
    float r2 = (o2 >= 0.f) ? o2 : 0.01f * o2;
    float res = (lane < D_OUT) ? (r1 + r2) : 0.f;

    float sq = res * res;
#pragma unroll
    for (int off = 32; off > 0; off >>= 1)
        sq += __shfl_xor(sq, off, 64);
    float nrm  = sqrtf(sq);
    float resn = res / fmaxf(nrm, 1e-12f);

    if (lane < D_OUT) {
        if (h_out) h_out[(size_t)wid * D_OUT + lane] = res;
        out_buf[(size_t)wid * OUT_STRIDE + out_col + lane] = resn;
    }
}

// ---------------------------------------------------------------------------
extern "C" void kernel_launch(void* const* d_in, const int* in_sizes, int n_in,
                              void* d_out, int out_size, void* d_ws, size_t ws_size,
                              hipStream_t stream) {
    const float* ent  = (const float*)d_in[0];
    const float* rel  = (const float*)d_in[1];
    const float* W_R  = (const float*)d_in[2];
    const float* W1_0 = (const float*)d_in[3];
    const float* b1_0 = (const float*)d_in[4];
    const float* W2_0 = (const float*)d_in[5];
    const float* b2_0 = (const float*)d_in[6];
    const float* W1_1 = (const float*)d_in[7];
    const float* b1_1 = (const float*)d_in[8];
    const float* W2_1 = (const float*)d_in[9];
    const float* b2_1 = (const float*)d_in[10];
    const float* W1_2 = (const float*)d_in[11];
    const float* b1_2 = (const float*)d_in[12];
    const float* W2_2 = (const float*)d_in[13];
    const float* b2_2 = (const float*)d_in[14];
    const int*   src   = (const int*)d_in[15];
    const int*   dst   = (const int*)d_in[16];
    const int*   etype = (const int*)d_in[17];
    float* out = (float*)d_out;

    // workspace layout
    char* w = (char*)d_ws;
    float* att_csr = (float*)w;  w += (size_t)N_EDGE * 4;          // 4 MB
    int*   src_csr = (int*)w;    w += (size_t)N_EDGE * 4;          // 4 MB
    int*   counts  = (int*)w;    w += (size_t)(N_ENT + 64) * 4;
    int*   row_ptr = (int*)w;    w += (size_t)(N_ENT + 64) * 4;
    int*   cursor  = (int*)w;    w += (size_t)(N_ENT + 64) * 4;
    float* h1      = (float*)w;  w += (size_t)N_ENT * 64 * 4;      // 12.8 MB
    float* h2      = (float*)w;  w += (size_t)N_ENT * 32 * 4;      // 6.4 MB
    __hip_bfloat16* proj = (__hip_bfloat16*)w;
    size_t need = (size_t)(w - (char*)d_ws) + (size_t)N_RELS * N_ENT * DIM * 2;

    hipMemsetAsync(counts, 0, (size_t)N_ENT * 4, stream);
    hipMemsetAsync(cursor, 0, (size_t)N_ENT * 4, stream);

    hist_kernel<<<(N_EDGE + 255) / 256, 256, 0, stream>>>(dst, counts, N_EDGE);
    scan_kernel<<<1, 1024, 0, stream>>>(counts, row_ptr, N_ENT);

    if (ws_size >= need) {
        // fast path: precompute proj, then gather-based edge pass
        proj_kernel<<<dim3(N_RELS, 64), 256, 0, stream>>>(ent, W_R, proj);
        att_edge_kernel<<<(N_EDGE + 3) / 4, 256, 0, stream>>>(
            proj, rel, src, dst, etype, row_ptr, cursor, att_csr, src_csr, N_EDGE);
    } else {
        att_kernel<<<(N_EDGE + 3) / 4, 256, 0, stream>>>(
            ent, rel, W_R, src, dst, etype, row_ptr, cursor, att_csr, src_csr, N_EDGE);
    }

    softmax_kernel<<<(N_ENT + 3) / 4, 256, 0, stream>>>(row_ptr, att_csr, N_ENT);
    copy_ent_kernel<<<(N_ENT * DIM + 255) / 256, 256, 0, stream>>>(ent, out, N_ENT * DIM);

    layer_kernel<64, 64><<<(N_ENT + 3) / 4, 256, 0, stream>>>(
        ent, W1_0, b1_0, W2_0, b2_0, row_ptr, att_csr, src_csr, h1, out, 64, N_ENT);
    layer_kernel<64, 32><<<(N_ENT + 3) / 4, 256, 0, stream>>>(
        h1, W1_1, b1_1, W2_1, b2_1, row_ptr, att_csr, src_csr, h2, out, 128, N_ENT);
    layer_kernel<32, 16><<<(N_ENT + 3) / 4, 256, 0, stream>>>(
        h2, W1_2, b1_2, W2_2, b2_2, row_ptr, att_csr, src_csr, nullptr, out, 160, N_ENT);
}